// Round 4
// baseline (586.743 us; speedup 1.0000x reference)
//
#include <hip/hip_runtime.h>

#define NN 50000
#define NE 600000
#define LN_EPS 1e-5f

// Module-level device scratch (graph-capture safe, no ws_size dependence).
__device__ __align__(16) float g_buf0[NN * 128];
__device__ __align__(16) float g_buf1[NN * 128];
__device__ int g_deg_out[NN];
__device__ int g_deg_in[NN];
__device__ float g_out_norm[NN];
__device__ float g_in_norm[NN];
__device__ int g_rowptr[NN + 1];
__device__ int g_cursor[NN];
__device__ int g_esrc[NE];

__device__ __forceinline__ float* gbuf(int i) { return i ? g_buf1 : g_buf0; }

__global__ __launch_bounds__(256) void zero_deg_kernel() {
    int i = blockIdx.x * 256 + threadIdx.x;
    if (i < NN) { g_deg_out[i] = 0; g_deg_in[i] = 0; }
}

__global__ __launch_bounds__(256) void deg_kernel(const int* __restrict__ src,
                                                  const int* __restrict__ dst) {
    int i = blockIdx.x * 256 + threadIdx.x;
    if (i < NE) {
        atomicAdd(&g_deg_out[src[i]], 1);
        atomicAdd(&g_deg_in[dst[i]], 1);
    }
}

__global__ __launch_bounds__(256) void norm_kernel() {
    int i = blockIdx.x * 256 + threadIdx.x;
    if (i < NN) {
        g_out_norm[i] = rsqrtf((float)max(g_deg_out[i], 1));
        g_in_norm[i]  = rsqrtf((float)max(g_deg_in[i], 1));
    }
}

// Exclusive prefix sum of g_deg_in -> g_rowptr / g_cursor. Single block.
__global__ __launch_bounds__(256) void scan_kernel() {
    __shared__ int partial[256];
    const int chunk = (NN + 255) / 256;  // 196
    int tid = threadIdx.x;
    int lo = tid * chunk;
    int hi = min(lo + chunk, NN);
    int s = 0;
    for (int i = lo; i < hi; ++i) s += g_deg_in[i];
    partial[tid] = s;
    __syncthreads();
    if (tid == 0) {
        int run = 0;
        for (int i = 0; i < 256; ++i) { int t = partial[i]; partial[i] = run; run += t; }
    }
    __syncthreads();
    int run = partial[tid];
    for (int i = lo; i < hi; ++i) {
        g_rowptr[i] = run;
        g_cursor[i] = run;
        run += g_deg_in[i];
    }
    if (tid == 255) g_rowptr[NN] = run;  // == NE
}

// CSR placement: for each edge, append src into its dst's segment (int atomics).
__global__ __launch_bounds__(256) void place_kernel(const int* __restrict__ src,
                                                    const int* __restrict__ dst) {
    int e = blockIdx.x * 256 + threadIdx.x;
    if (e < NE) {
        int pos = atomicAdd(&g_cursor[dst[e]], 1);
        g_esrc[pos] = src[e];
    }
}

// C[M x N] = (A * out_norm[:,None]) @ W.  A: [M x 128] f32 (Aext if non-null else gbuf(a_ib)),
// W: [128 x N] f32.  K split into two 64-phases. LDS 40KB (N=128) / 32KB (N=64).
template <int N>
__global__ __launch_bounds__(256) void gemm_scaled(const float* __restrict__ Aext,
                                                   int a_ib, int c_ib,
                                                   const float* __restrict__ Wg,
                                                   int M) {
    constexpr int TM = 4096 / N;   // 32 (N=128) or 64 (N=64)
    constexpr int CG = N / 4;      // float4 col-groups per row
    __shared__ float Wl[64 * N];
    __shared__ float Al[TM * 64];

    const int tid = threadIdx.x;
    const int row0 = blockIdx.x * TM;
    const int tr = tid / CG;
    const int tc = tid % CG;
    const int r0 = tr * 4;

    float acc[4][4] = {};
    const float4* A4 = (const float4*)(Aext ? Aext : gbuf(a_ib));
    float* C = gbuf(c_ib);
    const float4* W4 = (const float4*)Wg;

    for (int ph = 0; ph < 2; ++ph) {
        // stage W rows [ph*64, ph*64+64) x N
        for (int i = tid; i < 64 * N / 4; i += 256) {
            ((float4*)Wl)[i] = W4[ph * 16 * N + i];
        }
        // stage A tile [TM x 64] scaled by out_norm
        for (int i = tid; i < TM * 16; i += 256) {
            int r = i >> 4, c4 = i & 15;
            int gr = row0 + r;
            float4 v = make_float4(0.f, 0.f, 0.f, 0.f);
            if (gr < M) {
                float s = g_out_norm[gr];
                v = A4[gr * 32 + ph * 16 + c4];
                v.x *= s; v.y *= s; v.z *= s; v.w *= s;
            }
            ((float4*)Al)[i] = v;
        }
        __syncthreads();

        const float4* Al4 = (const float4*)Al;
        const float4* Wl4 = (const float4*)Wl;
#pragma unroll 2
        for (int kk = 0; kk < 16; ++kk) {
            float4 a[4], w[4];
#pragma unroll
            for (int i = 0; i < 4; ++i) a[i] = Al4[(r0 + i) * 16 + kk];
#pragma unroll
            for (int j = 0; j < 4; ++j) w[j] = Wl4[(4 * kk + j) * CG + tc];
#pragma unroll
            for (int i = 0; i < 4; ++i) {
                acc[i][0] += a[i].x * w[0].x + a[i].y * w[1].x + a[i].z * w[2].x + a[i].w * w[3].x;
                acc[i][1] += a[i].x * w[0].y + a[i].y * w[1].y + a[i].z * w[2].y + a[i].w * w[3].y;
                acc[i][2] += a[i].x * w[0].z + a[i].y * w[1].z + a[i].z * w[2].z + a[i].w * w[3].z;
                acc[i][3] += a[i].x * w[0].w + a[i].y * w[1].w + a[i].z * w[2].w + a[i].w * w[3].w;
            }
        }
        __syncthreads();
    }

#pragma unroll
    for (int i = 0; i < 4; ++i) {
        int gr = row0 + r0 + i;
        if (gr < M) {
            float4 o = make_float4(acc[i][0], acc[i][1], acc[i][2], acc[i][3]);
            ((float4*)C)[gr * CG + tc] = o;
        }
    }
}

// Fused: gather(CSR) -> *in_norm + b -> relu -> LayerNorm -> write. 1 wave/node, D=128.
__global__ __launch_bounds__(256) void gather_ln_kernel(int s_ib, int d_ib,
                                                        const float* __restrict__ b,
                                                        const float* __restrict__ ln_s,
                                                        const float* __restrict__ ln_b) {
    int wave = threadIdx.x >> 6;
    int lane = threadIdx.x & 63;
    int node = blockIdx.x * 4 + wave;
    if (node >= NN) return;
    const float2* H2 = (const float2*)gbuf(s_ib);
    int beg = g_rowptr[node], end = g_rowptr[node + 1];
    float2 acc = make_float2(0.f, 0.f);
    for (int j = beg; j < end; ++j) {
        int s = g_esrc[j];
        float2 v = H2[s * 64 + lane];
        acc.x += v.x; acc.y += v.y;
    }
    float nrm = g_in_norm[node];
    int c = lane * 2;
    float vx = fmaxf(acc.x * nrm + b[c], 0.f);
    float vy = fmaxf(acc.y * nrm + b[c + 1], 0.f);
    float s = vx + vy;
    float sq = vx * vx + vy * vy;
#pragma unroll
    for (int off = 32; off > 0; off >>= 1) {
        s  += __shfl_xor(s, off, 64);
        sq += __shfl_xor(sq, off, 64);
    }
    float mean = s * (1.f / 128.f);
    float var = sq * (1.f / 128.f) - mean * mean;
    float inv = rsqrtf(var + LN_EPS);
    float2 o;
    o.x = (vx - mean) * inv * ln_s[c] + ln_b[c];
    o.y = (vy - mean) * inv * ln_s[c + 1] + ln_b[c + 1];
    ((float2*)gbuf(d_ib))[node * 64 + lane] = o;
}

// Fused final: gather(CSR, D=64) -> *in_norm + b2 -> relu -> f32 store. 1 wave/node.
__global__ __launch_bounds__(256) void GCN_63831803953156_kernel(int s_ib,
                                                                 const float* __restrict__ b2,
                                                                 float* __restrict__ out) {
    int wave = threadIdx.x >> 6;
    int lane = threadIdx.x & 63;
    int node = blockIdx.x * 4 + wave;
    if (node >= NN) return;
    const float* H = gbuf(s_ib);
    int beg = g_rowptr[node], end = g_rowptr[node + 1];
    float acc = 0.f;
    for (int j = beg; j < end; ++j) {
        int s = g_esrc[j];
        acc += H[s * 64 + lane];
    }
    float v = fmaxf(acc * g_in_norm[node] + b2[lane], 0.f);
    out[node * 64 + lane] = v;
}

extern "C" void kernel_launch(void* const* d_in, const int* in_sizes, int n_in,
                              void* d_out, int out_size, void* d_ws, size_t ws_size,
                              hipStream_t stream) {
    const float* x   = (const float*)d_in[0];
    const int* src   = (const int*)d_in[1];
    const int* dst   = (const int*)d_in[2];
    const float* W0  = (const float*)d_in[3];
    const float* b0  = (const float*)d_in[4];
    const float* W1  = (const float*)d_in[5];
    const float* b1  = (const float*)d_in[6];
    const float* W2  = (const float*)d_in[7];
    const float* b2  = (const float*)d_in[8];
    const float* ln_s = (const float*)d_in[9];
    const float* ln_b = (const float*)d_in[10];
    (void)d_ws; (void)ws_size; (void)in_sizes; (void)n_in; (void)out_size;

    // degrees, norms, CSR
    zero_deg_kernel<<<(NN + 255) / 256, 256, 0, stream>>>();
    deg_kernel<<<(NE + 255) / 256, 256, 0, stream>>>(src, dst);
    norm_kernel<<<(NN + 255) / 256, 256, 0, stream>>>();
    scan_kernel<<<1, 256, 0, stream>>>();
    place_kernel<<<(NE + 255) / 256, 256, 0, stream>>>(src, dst);

    // layer 0: gemm X->B0, fused gather+LN B0->B1
    gemm_scaled<128><<<(NN + 31) / 32, 256, 0, stream>>>(x, -1, 0, W0, NN);
    gather_ln_kernel<<<(NN + 3) / 4, 256, 0, stream>>>(0, 1, b0, ln_s, ln_b);

    // layer 1: gemm B1->B0, fused gather+LN B0->B1
    gemm_scaled<128><<<(NN + 31) / 32, 256, 0, stream>>>(nullptr, 1, 0, W1, NN);
    gather_ln_kernel<<<(NN + 3) / 4, 256, 0, stream>>>(0, 1, b1, ln_s, ln_b);

    // layer 2 (128->64): gemm B1->B0, fused gather+relu B0->out
    gemm_scaled<64><<<(NN + 63) / 64, 256, 0, stream>>>(nullptr, 1, 0, W2, NN);
    GCN_63831803953156_kernel<<<(NN + 3) / 4, 256, 0, stream>>>(0, b2, (float*)d_out);
}

// Round 5
// 468.064 us; speedup vs baseline: 1.2536x; 1.2536x over previous
//
#include <hip/hip_runtime.h>

#define NN 50000
#define NE 600000
#define LN_EPS 1e-5f
#define SCAN_B 49   // 49 blocks x 1024 elements covers 50176 >= NN

// Module-level device scratch (graph-capture safe, no ws_size dependence).
__device__ __align__(16) float g_buf0[NN * 128];
__device__ __align__(16) float g_buf1[NN * 128];
__device__ int g_deg_out[NN];
__device__ __align__(16) int g_deg_in[NN];
__device__ float g_out_norm[NN];
__device__ float g_in_norm[NN];
__device__ int g_rowptr[NN + 1];
__device__ int g_cursor[NN];
__device__ int g_esrc[NE];
__device__ int g_blocksum[SCAN_B];
__device__ int g_blockoff[SCAN_B];

__device__ __forceinline__ float* gbuf(int i) { return i ? g_buf1 : g_buf0; }

__global__ __launch_bounds__(256) void zero_deg_kernel() {
    int i = blockIdx.x * 256 + threadIdx.x;
    if (i < NN) { g_deg_out[i] = 0; g_deg_in[i] = 0; }
}

__global__ __launch_bounds__(256) void deg_kernel(const int* __restrict__ src,
                                                  const int* __restrict__ dst) {
    int i = blockIdx.x * 256 + threadIdx.x;
    if (i < NE) {
        atomicAdd(&g_deg_out[src[i]], 1);
        atomicAdd(&g_deg_in[dst[i]], 1);
    }
}

__global__ __launch_bounds__(256) void norm_kernel() {
    int i = blockIdx.x * 256 + threadIdx.x;
    if (i < NN) {
        g_out_norm[i] = rsqrtf((float)max(g_deg_out[i], 1));
        g_in_norm[i]  = rsqrtf((float)max(g_deg_in[i], 1));
    }
}

// ---- 3-phase parallel exclusive scan of g_deg_in -> g_rowptr / g_cursor ----

// Phase 1: block b sums deg_in[b*1024 .. b*1024+1024) -> g_blocksum[b]
__global__ __launch_bounds__(256) void scan_phase1() {
    __shared__ int wsum[4];
    int b = blockIdx.x, t = threadIdx.x;
    int base = b * 1024 + t * 4;
    int s = 0;
    if (base + 3 < NN) {
        int4 v = *(const int4*)&g_deg_in[base];
        s = v.x + v.y + v.z + v.w;
    } else {
#pragma unroll
        for (int k = 0; k < 4; ++k)
            if (base + k < NN) s += g_deg_in[base + k];
    }
#pragma unroll
    for (int off = 32; off; off >>= 1) s += __shfl_xor(s, off, 64);
    if ((t & 63) == 0) wsum[t >> 6] = s;
    __syncthreads();
    if (t == 0) g_blocksum[b] = wsum[0] + wsum[1] + wsum[2] + wsum[3];
}

// Phase 2: one wave scans the 49 block sums -> exclusive g_blockoff; rowptr[NN]=NE
__global__ __launch_bounds__(64) void scan_phase2() {
    int lane = threadIdx.x;
    int own = (lane < SCAN_B) ? g_blocksum[lane] : 0;
    int v = own;
#pragma unroll
    for (int off = 1; off < 64; off <<= 1) {
        int n = __shfl_up(v, off, 64);
        if (lane >= off) v += n;
    }
    if (lane < SCAN_B) g_blockoff[lane] = v - own;
    if (lane == SCAN_B - 1) g_rowptr[NN] = v;   // total == NE
}

// Phase 3: block b writes exclusive scan for its 1024 elements
__global__ __launch_bounds__(256) void scan_phase3() {
    __shared__ int sums[256];
    int b = blockIdx.x, t = threadIdx.x;
    int base = b * 1024 + t * 4;
    int v[4];
#pragma unroll
    for (int k = 0; k < 4; ++k) v[k] = (base + k < NN) ? g_deg_in[base + k] : 0;
    int tsum = v[0] + v[1] + v[2] + v[3];
    sums[t] = tsum;
    __syncthreads();
    // Hillis-Steele inclusive scan over 256 per-thread sums
    for (int off = 1; off < 256; off <<= 1) {
        int add = (t >= off) ? sums[t - off] : 0;
        __syncthreads();
        sums[t] += add;
        __syncthreads();
    }
    int excl = sums[t] - tsum + g_blockoff[b];
#pragma unroll
    for (int k = 0; k < 4; ++k) {
        int idx = base + k;
        if (idx < NN) { g_rowptr[idx] = excl; g_cursor[idx] = excl; }
        excl += v[k];
    }
}

// CSR placement: for each edge, append src into its dst's segment (int atomics).
__global__ __launch_bounds__(256) void place_kernel(const int* __restrict__ src,
                                                    const int* __restrict__ dst) {
    int e = blockIdx.x * 256 + threadIdx.x;
    if (e < NE) {
        int pos = atomicAdd(&g_cursor[dst[e]], 1);
        g_esrc[pos] = src[e];
    }
}

// C[M x N] = (A * out_norm[:,None]) @ W.  A: [M x 128] f32 (Aext if non-null else gbuf(a_ib)),
// W: [128 x N] f32.  K split into two 64-phases. LDS 40KB (N=128) / 32KB (N=64).
template <int N>
__global__ __launch_bounds__(256) void gemm_scaled(const float* __restrict__ Aext,
                                                   int a_ib, int c_ib,
                                                   const float* __restrict__ Wg,
                                                   int M) {
    constexpr int TM = 4096 / N;   // 32 (N=128) or 64 (N=64)
    constexpr int CG = N / 4;      // float4 col-groups per row
    __shared__ float Wl[64 * N];
    __shared__ float Al[TM * 64];

    const int tid = threadIdx.x;
    const int row0 = blockIdx.x * TM;
    const int tr = tid / CG;
    const int tc = tid % CG;
    const int r0 = tr * 4;

    float acc[4][4] = {};
    const float4* A4 = (const float4*)(Aext ? Aext : gbuf(a_ib));
    float* C = gbuf(c_ib);
    const float4* W4 = (const float4*)Wg;

    for (int ph = 0; ph < 2; ++ph) {
        for (int i = tid; i < 64 * N / 4; i += 256) {
            ((float4*)Wl)[i] = W4[ph * 16 * N + i];
        }
        for (int i = tid; i < TM * 16; i += 256) {
            int r = i >> 4, c4 = i & 15;
            int gr = row0 + r;
            float4 v = make_float4(0.f, 0.f, 0.f, 0.f);
            if (gr < M) {
                float s = g_out_norm[gr];
                v = A4[gr * 32 + ph * 16 + c4];
                v.x *= s; v.y *= s; v.z *= s; v.w *= s;
            }
            ((float4*)Al)[i] = v;
        }
        __syncthreads();

        const float4* Al4 = (const float4*)Al;
        const float4* Wl4 = (const float4*)Wl;
#pragma unroll 2
        for (int kk = 0; kk < 16; ++kk) {
            float4 a[4], w[4];
#pragma unroll
            for (int i = 0; i < 4; ++i) a[i] = Al4[(r0 + i) * 16 + kk];
#pragma unroll
            for (int j = 0; j < 4; ++j) w[j] = Wl4[(4 * kk + j) * CG + tc];
#pragma unroll
            for (int i = 0; i < 4; ++i) {
                acc[i][0] += a[i].x * w[0].x + a[i].y * w[1].x + a[i].z * w[2].x + a[i].w * w[3].x;
                acc[i][1] += a[i].x * w[0].y + a[i].y * w[1].y + a[i].z * w[2].y + a[i].w * w[3].y;
                acc[i][2] += a[i].x * w[0].z + a[i].y * w[1].z + a[i].z * w[2].z + a[i].w * w[3].z;
                acc[i][3] += a[i].x * w[0].w + a[i].y * w[1].w + a[i].z * w[2].w + a[i].w * w[3].w;
            }
        }
        __syncthreads();
    }

#pragma unroll
    for (int i = 0; i < 4; ++i) {
        int gr = row0 + r0 + i;
        if (gr < M) {
            float4 o = make_float4(acc[i][0], acc[i][1], acc[i][2], acc[i][3]);
            ((float4*)C)[gr * CG + tc] = o;
        }
    }
}

// Fused: gather(CSR) -> *in_norm + b -> relu -> LayerNorm -> write. 1 wave/node, D=128.
__global__ __launch_bounds__(256) void gather_ln_kernel(int s_ib, int d_ib,
                                                        const float* __restrict__ b,
                                                        const float* __restrict__ ln_s,
                                                        const float* __restrict__ ln_b) {
    int wave = threadIdx.x >> 6;
    int lane = threadIdx.x & 63;
    int node = blockIdx.x * 4 + wave;
    if (node >= NN) return;
    const float2* H2 = (const float2*)gbuf(s_ib);
    int beg = g_rowptr[node], end = g_rowptr[node + 1];
    float2 acc = make_float2(0.f, 0.f);
    for (int j = beg; j < end; ++j) {
        int s = g_esrc[j];
        float2 v = H2[s * 64 + lane];
        acc.x += v.x; acc.y += v.y;
    }
    float nrm = g_in_norm[node];
    int c = lane * 2;
    float vx = fmaxf(acc.x * nrm + b[c], 0.f);
    float vy = fmaxf(acc.y * nrm + b[c + 1], 0.f);
    float s = vx + vy;
    float sq = vx * vx + vy * vy;
#pragma unroll
    for (int off = 32; off > 0; off >>= 1) {
        s  += __shfl_xor(s, off, 64);
        sq += __shfl_xor(sq, off, 64);
    }
    float mean = s * (1.f / 128.f);
    float var = sq * (1.f / 128.f) - mean * mean;
    float inv = rsqrtf(var + LN_EPS);
    float2 o;
    o.x = (vx - mean) * inv * ln_s[c] + ln_b[c];
    o.y = (vy - mean) * inv * ln_s[c + 1] + ln_b[c + 1];
    ((float2*)gbuf(d_ib))[node * 64 + lane] = o;
}

// Fused final: gather(CSR, D=64) -> *in_norm + b2 -> relu -> f32 store. 1 wave/node.
__global__ __launch_bounds__(256) void GCN_63831803953156_kernel(int s_ib,
                                                                 const float* __restrict__ b2,
                                                                 float* __restrict__ out) {
    int wave = threadIdx.x >> 6;
    int lane = threadIdx.x & 63;
    int node = blockIdx.x * 4 + wave;
    if (node >= NN) return;
    const float* H = gbuf(s_ib);
    int beg = g_rowptr[node], end = g_rowptr[node + 1];
    float acc = 0.f;
    for (int j = beg; j < end; ++j) {
        int s = g_esrc[j];
        acc += H[s * 64 + lane];
    }
    float v = fmaxf(acc * g_in_norm[node] + b2[lane], 0.f);
    out[node * 64 + lane] = v;
}

extern "C" void kernel_launch(void* const* d_in, const int* in_sizes, int n_in,
                              void* d_out, int out_size, void* d_ws, size_t ws_size,
                              hipStream_t stream) {
    const float* x   = (const float*)d_in[0];
    const int* src   = (const int*)d_in[1];
    const int* dst   = (const int*)d_in[2];
    const float* W0  = (const float*)d_in[3];
    const float* b0  = (const float*)d_in[4];
    const float* W1  = (const float*)d_in[5];
    const float* b1  = (const float*)d_in[6];
    const float* W2  = (const float*)d_in[7];
    const float* b2  = (const float*)d_in[8];
    const float* ln_s = (const float*)d_in[9];
    const float* ln_b = (const float*)d_in[10];
    (void)d_ws; (void)ws_size; (void)in_sizes; (void)n_in; (void)out_size;

    // degrees, norms, CSR (parallel scan)
    zero_deg_kernel<<<(NN + 255) / 256, 256, 0, stream>>>();
    deg_kernel<<<(NE + 255) / 256, 256, 0, stream>>>(src, dst);
    norm_kernel<<<(NN + 255) / 256, 256, 0, stream>>>();
    scan_phase1<<<SCAN_B, 256, 0, stream>>>();
    scan_phase2<<<1, 64, 0, stream>>>();
    scan_phase3<<<SCAN_B, 256, 0, stream>>>();
    place_kernel<<<(NE + 255) / 256, 256, 0, stream>>>(src, dst);

    // layer 0: gemm X->B0, fused gather+LN B0->B1
    gemm_scaled<128><<<(NN + 31) / 32, 256, 0, stream>>>(x, -1, 0, W0, NN);
    gather_ln_kernel<<<(NN + 3) / 4, 256, 0, stream>>>(0, 1, b0, ln_s, ln_b);

    // layer 1: gemm B1->B0, fused gather+LN B0->B1
    gemm_scaled<128><<<(NN + 31) / 32, 256, 0, stream>>>(nullptr, 1, 0, W1, NN);
    gather_ln_kernel<<<(NN + 3) / 4, 256, 0, stream>>>(0, 1, b1, ln_s, ln_b);

    // layer 2 (128->64): gemm B1->B0, fused gather+relu B0->out
    gemm_scaled<64><<<(NN + 63) / 64, 256, 0, stream>>>(nullptr, 1, 0, W2, NN);
    GCN_63831803953156_kernel<<<(NN + 3) / 4, 256, 0, stream>>>(0, b2, (float*)d_out);
}

// Round 6
// 372.364 us; speedup vs baseline: 1.5757x; 1.2570x over previous
//
#include <hip/hip_runtime.h>
#include <hip/hip_fp16.h>

#define NN 50000
#define NE 600000
#define LN_EPS 1e-5f
#define SCAN_B 49   // 49 blocks x 1024 elements covers 50176 >= NN

// Module-level device scratch (graph-capture safe).
// Intermediate H buffers in fp16 (halves gather/GEMM traffic; fp32 accumulate).
__device__ __align__(16) __half g_h0[NN * 128];
__device__ __align__(16) __half g_h1[NN * 128];
__device__ int g_deg_out[NN];
__device__ __align__(16) int g_deg_in[NN];
__device__ float g_out_norm[NN];
__device__ float g_in_norm[NN];
__device__ int g_rowptr[NN + 1];
__device__ int g_cursor[NN];
__device__ int g_esrc[NE];
__device__ int g_blocksum[SCAN_B];
__device__ int g_blockoff[SCAN_B];

__device__ __forceinline__ __half* hbuf(int i) { return i ? g_h1 : g_h0; }

__global__ __launch_bounds__(256) void zero_deg_kernel() {
    int i = blockIdx.x * 256 + threadIdx.x;
    if (i < NN) { g_deg_out[i] = 0; g_deg_in[i] = 0; }
}

__global__ __launch_bounds__(256) void deg_kernel(const int* __restrict__ src,
                                                  const int* __restrict__ dst) {
    int i = blockIdx.x * 256 + threadIdx.x;
    if (i < NE) {
        atomicAdd(&g_deg_out[src[i]], 1);
        atomicAdd(&g_deg_in[dst[i]], 1);
    }
}

__global__ __launch_bounds__(256) void norm_kernel() {
    int i = blockIdx.x * 256 + threadIdx.x;
    if (i < NN) {
        g_out_norm[i] = rsqrtf((float)max(g_deg_out[i], 1));
        g_in_norm[i]  = rsqrtf((float)max(g_deg_in[i], 1));
    }
}

// ---- 3-phase parallel exclusive scan of g_deg_in -> g_rowptr / g_cursor ----
__global__ __launch_bounds__(256) void scan_phase1() {
    __shared__ int wsum[4];
    int b = blockIdx.x, t = threadIdx.x;
    int base = b * 1024 + t * 4;
    int s = 0;
    if (base + 3 < NN) {
        int4 v = *(const int4*)&g_deg_in[base];
        s = v.x + v.y + v.z + v.w;
    } else {
#pragma unroll
        for (int k = 0; k < 4; ++k)
            if (base + k < NN) s += g_deg_in[base + k];
    }
#pragma unroll
    for (int off = 32; off; off >>= 1) s += __shfl_xor(s, off, 64);
    if ((t & 63) == 0) wsum[t >> 6] = s;
    __syncthreads();
    if (t == 0) g_blocksum[b] = wsum[0] + wsum[1] + wsum[2] + wsum[3];
}

__global__ __launch_bounds__(64) void scan_phase2() {
    int lane = threadIdx.x;
    int own = (lane < SCAN_B) ? g_blocksum[lane] : 0;
    int v = own;
#pragma unroll
    for (int off = 1; off < 64; off <<= 1) {
        int n = __shfl_up(v, off, 64);
        if (lane >= off) v += n;
    }
    if (lane < SCAN_B) g_blockoff[lane] = v - own;
    if (lane == SCAN_B - 1) g_rowptr[NN] = v;   // total == NE
}

__global__ __launch_bounds__(256) void scan_phase3() {
    __shared__ int sums[256];
    int b = blockIdx.x, t = threadIdx.x;
    int base = b * 1024 + t * 4;
    int v[4];
#pragma unroll
    for (int k = 0; k < 4; ++k) v[k] = (base + k < NN) ? g_deg_in[base + k] : 0;
    int tsum = v[0] + v[1] + v[2] + v[3];
    sums[t] = tsum;
    __syncthreads();
    for (int off = 1; off < 256; off <<= 1) {
        int add = (t >= off) ? sums[t - off] : 0;
        __syncthreads();
        sums[t] += add;
        __syncthreads();
    }
    int excl = sums[t] - tsum + g_blockoff[b];
#pragma unroll
    for (int k = 0; k < 4; ++k) {
        int idx = base + k;
        if (idx < NN) { g_rowptr[idx] = excl; g_cursor[idx] = excl; }
        excl += v[k];
    }
}

__global__ __launch_bounds__(256) void place_kernel(const int* __restrict__ src,
                                                    const int* __restrict__ dst) {
    int e = blockIdx.x * 256 + threadIdx.x;
    if (e < NE) {
        int pos = atomicAdd(&g_cursor[dst[e]], 1);
        g_esrc[pos] = src[e];
    }
}

// C[M x N](fp16) = (A * out_norm[:,None]) @ W.
// A: fp32 ext (layer 0) or fp16 hbuf. W: [128 x N] fp32. fp32 accumulate.
template <int N, bool AEXT>
__global__ __launch_bounds__(256) void gemm_scaled(const float* __restrict__ Aext,
                                                   int a_ib, int c_ib,
                                                   const float* __restrict__ Wg,
                                                   int M) {
    constexpr int TM = 4096 / N;   // 32 (N=128) or 64 (N=64)
    constexpr int CG = N / 4;      // 4-col groups per row
    __shared__ float Wl[64 * N];
    __shared__ float Al[TM * 64];

    const int tid = threadIdx.x;
    const int row0 = blockIdx.x * TM;
    const int tr = tid / CG;
    const int tc = tid % CG;
    const int r0 = tr * 4;

    float acc[4][4] = {};
    const float4* W4 = (const float4*)Wg;
    const float4* A4 = AEXT ? (const float4*)Aext : nullptr;
    const uint2* Ah = AEXT ? nullptr : (const uint2*)hbuf(a_ib);
    __half* C = hbuf(c_ib);

    for (int ph = 0; ph < 2; ++ph) {
        for (int i = tid; i < 64 * N / 4; i += 256) {
            ((float4*)Wl)[i] = W4[ph * 16 * N + i];
        }
        for (int i = tid; i < TM * 16; i += 256) {
            int r = i >> 4, c4 = i & 15;
            int gr = row0 + r;
            float4 v = make_float4(0.f, 0.f, 0.f, 0.f);
            if (gr < M) {
                float s = g_out_norm[gr];
                if (AEXT) {
                    v = A4[gr * 32 + ph * 16 + c4];
                } else {
                    uint2 u = Ah[gr * 32 + ph * 16 + c4];
                    float2 f0 = __half22float2(*(const __half2*)&u.x);
                    float2 f1 = __half22float2(*(const __half2*)&u.y);
                    v = make_float4(f0.x, f0.y, f1.x, f1.y);
                }
                v.x *= s; v.y *= s; v.z *= s; v.w *= s;
            }
            ((float4*)Al)[i] = v;
        }
        __syncthreads();

        const float4* Al4 = (const float4*)Al;
        const float4* Wl4 = (const float4*)Wl;
#pragma unroll 2
        for (int kk = 0; kk < 16; ++kk) {
            float4 a[4], w[4];
#pragma unroll
            for (int i = 0; i < 4; ++i) a[i] = Al4[(r0 + i) * 16 + kk];
#pragma unroll
            for (int j = 0; j < 4; ++j) w[j] = Wl4[(4 * kk + j) * CG + tc];
#pragma unroll
            for (int i = 0; i < 4; ++i) {
                acc[i][0] += a[i].x * w[0].x + a[i].y * w[1].x + a[i].z * w[2].x + a[i].w * w[3].x;
                acc[i][1] += a[i].x * w[0].y + a[i].y * w[1].y + a[i].z * w[2].y + a[i].w * w[3].y;
                acc[i][2] += a[i].x * w[0].z + a[i].y * w[1].z + a[i].z * w[2].z + a[i].w * w[3].z;
                acc[i][3] += a[i].x * w[0].w + a[i].y * w[1].w + a[i].z * w[2].w + a[i].w * w[3].w;
            }
        }
        __syncthreads();
    }

#pragma unroll
    for (int i = 0; i < 4; ++i) {
        int gr = row0 + r0 + i;
        if (gr < M) {
            __half2 ha = __floats2half2_rn(acc[i][0], acc[i][1]);
            __half2 hb = __floats2half2_rn(acc[i][2], acc[i][3]);
            uint2 o = make_uint2(*(const unsigned int*)&ha, *(const unsigned int*)&hb);
            ((uint2*)C)[gr * CG + tc] = o;
        }
    }
}

// Fused: gather(CSR, fp16 128-dim) -> *in_norm + b -> relu -> LN -> fp16 write. 1 wave/node.
__global__ __launch_bounds__(256) void gather_ln_kernel(int s_ib, int d_ib,
                                                        const float* __restrict__ b,
                                                        const float* __restrict__ ln_s,
                                                        const float* __restrict__ ln_b) {
    int wave = threadIdx.x >> 6;
    int lane = threadIdx.x & 63;
    int node = blockIdx.x * 4 + wave;
    if (node >= NN) return;
    const unsigned int* Hu = (const unsigned int*)hbuf(s_ib);  // half2 per lane, 64/row
    int beg = g_rowptr[node], end = g_rowptr[node + 1];
    float ax = 0.f, ay = 0.f;
    int j = beg;
    for (; j + 3 < end; j += 4) {
        int s0 = g_esrc[j], s1 = g_esrc[j + 1], s2 = g_esrc[j + 2], s3 = g_esrc[j + 3];
        unsigned int u0 = Hu[s0 * 64 + lane];
        unsigned int u1 = Hu[s1 * 64 + lane];
        unsigned int u2 = Hu[s2 * 64 + lane];
        unsigned int u3 = Hu[s3 * 64 + lane];
        float2 f0 = __half22float2(*(const __half2*)&u0);
        float2 f1 = __half22float2(*(const __half2*)&u1);
        float2 f2 = __half22float2(*(const __half2*)&u2);
        float2 f3 = __half22float2(*(const __half2*)&u3);
        ax += (f0.x + f1.x) + (f2.x + f3.x);
        ay += (f0.y + f1.y) + (f2.y + f3.y);
    }
    for (; j < end; ++j) {
        unsigned int u = Hu[g_esrc[j] * 64 + lane];
        float2 f = __half22float2(*(const __half2*)&u);
        ax += f.x; ay += f.y;
    }
    float nrm = g_in_norm[node];
    int c = lane * 2;
    float vx = fmaxf(ax * nrm + b[c], 0.f);
    float vy = fmaxf(ay * nrm + b[c + 1], 0.f);
    float s = vx + vy;
    float sq = vx * vx + vy * vy;
#pragma unroll
    for (int off = 32; off > 0; off >>= 1) {
        s  += __shfl_xor(s, off, 64);
        sq += __shfl_xor(sq, off, 64);
    }
    float mean = s * (1.f / 128.f);
    float var = sq * (1.f / 128.f) - mean * mean;
    float inv = rsqrtf(var + LN_EPS);
    float ox = (vx - mean) * inv * ln_s[c] + ln_b[c];
    float oy = (vy - mean) * inv * ln_s[c + 1] + ln_b[c + 1];
    __half2 h = __floats2half2_rn(ox, oy);
    ((unsigned int*)hbuf(d_ib))[node * 64 + lane] = *(const unsigned int*)&h;
}

// Fused final: gather(CSR, fp16 64-dim) -> *in_norm + b2 -> relu -> fp32 out. 1 wave/node.
__global__ __launch_bounds__(256) void GCN_63831803953156_kernel(int s_ib,
                                                                 const float* __restrict__ b2,
                                                                 float* __restrict__ out) {
    int wave = threadIdx.x >> 6;
    int lane = threadIdx.x & 63;
    int node = blockIdx.x * 4 + wave;
    if (node >= NN) return;
    const unsigned short* Hs = (const unsigned short*)hbuf(s_ib);  // 1 half per lane, 64/row
    int beg = g_rowptr[node], end = g_rowptr[node + 1];
    float acc = 0.f;
    int j = beg;
    for (; j + 3 < end; j += 4) {
        int s0 = g_esrc[j], s1 = g_esrc[j + 1], s2 = g_esrc[j + 2], s3 = g_esrc[j + 3];
        unsigned short u0 = Hs[s0 * 64 + lane];
        unsigned short u1 = Hs[s1 * 64 + lane];
        unsigned short u2 = Hs[s2 * 64 + lane];
        unsigned short u3 = Hs[s3 * 64 + lane];
        acc += (__half2float(*(const __half*)&u0) + __half2float(*(const __half*)&u1)) +
               (__half2float(*(const __half*)&u2) + __half2float(*(const __half*)&u3));
    }
    for (; j < end; ++j) {
        unsigned short u = Hs[g_esrc[j] * 64 + lane];
        acc += __half2float(*(const __half*)&u);
    }
    float v = fmaxf(acc * g_in_norm[node] + b2[lane], 0.f);
    out[node * 64 + lane] = v;
}

extern "C" void kernel_launch(void* const* d_in, const int* in_sizes, int n_in,
                              void* d_out, int out_size, void* d_ws, size_t ws_size,
                              hipStream_t stream) {
    const float* x   = (const float*)d_in[0];
    const int* src   = (const int*)d_in[1];
    const int* dst   = (const int*)d_in[2];
    const float* W0  = (const float*)d_in[3];
    const float* b0  = (const float*)d_in[4];
    const float* W1  = (const float*)d_in[5];
    const float* b1  = (const float*)d_in[6];
    const float* W2  = (const float*)d_in[7];
    const float* b2  = (const float*)d_in[8];
    const float* ln_s = (const float*)d_in[9];
    const float* ln_b = (const float*)d_in[10];
    (void)d_ws; (void)ws_size; (void)in_sizes; (void)n_in; (void)out_size;

    // degrees, norms, CSR (parallel scan)
    zero_deg_kernel<<<(NN + 255) / 256, 256, 0, stream>>>();
    deg_kernel<<<(NE + 255) / 256, 256, 0, stream>>>(src, dst);
    norm_kernel<<<(NN + 255) / 256, 256, 0, stream>>>();
    scan_phase1<<<SCAN_B, 256, 0, stream>>>();
    scan_phase2<<<1, 64, 0, stream>>>();
    scan_phase3<<<SCAN_B, 256, 0, stream>>>();
    place_kernel<<<(NE + 255) / 256, 256, 0, stream>>>(src, dst);

    // layer 0: gemm X->H0, fused gather+LN H0->H1
    gemm_scaled<128, true><<<(NN + 31) / 32, 256, 0, stream>>>(x, -1, 0, W0, NN);
    gather_ln_kernel<<<(NN + 3) / 4, 256, 0, stream>>>(0, 1, b0, ln_s, ln_b);

    // layer 1: gemm H1->H0, fused gather+LN H0->H1
    gemm_scaled<128, false><<<(NN + 31) / 32, 256, 0, stream>>>(nullptr, 1, 0, W1, NN);
    gather_ln_kernel<<<(NN + 3) / 4, 256, 0, stream>>>(0, 1, b1, ln_s, ln_b);

    // layer 2 (128->64): gemm H1->H0, fused gather+relu H0->out
    gemm_scaled<64, false><<<(NN + 63) / 64, 256, 0, stream>>>(nullptr, 1, 0, W2, NN);
    GCN_63831803953156_kernel<<<(NN + 3) / 4, 256, 0, stream>>>(0, b2, (float*)d_out);
}

// Round 7
// 341.701 us; speedup vs baseline: 1.7171x; 1.0897x over previous
//
#include <hip/hip_runtime.h>
#include <hip/hip_fp16.h>

#define NN 50000
#define NE 600000
#define LN_EPS 1e-5f
#define SCAN_B 49    // 49 blocks x 1024 elements covers 50176 >= NN
#define RANGES 8     // node ranges of 6250 (8*6250 = 50000)
#define RSZ 6250
#define CHUNKS 16    // edge chunks of 37500 (16*37500 = 600000)
#define CSZ 37500

// Module-level device scratch (graph-capture safe).
__device__ __align__(16) __half g_h0[NN * 128];
__device__ __align__(16) __half g_h1[NN * 128];
__device__ __align__(16) int g_deg_in[NN];
__device__ float g_out_norm[NN];
__device__ float g_in_norm[NN];
__device__ int g_rowptr[NN + 1];
__device__ int g_esrc[NE];
__device__ int g_blocksum[SCAN_B];
__device__ int g_blockoff[SCAN_B];
// CSR-build privatized partials (no device-scope atomics in the hot path)
__device__ int g_pout[CHUNKS * NN];
__device__ int g_pin[CHUNKS * NN];
__device__ int g_base[CHUNKS * NN];

__device__ __forceinline__ __half* hbuf(int i) { return i ? g_h1 : g_h0; }

// ---- Pass A: privatized histograms. Block (c,r): LDS-count chunk c's edges in range r ----
__global__ __launch_bounds__(256) void histo_kernel(const int* __restrict__ src,
                                                    const int* __restrict__ dst) {
    __shared__ int h_out[RSZ];
    __shared__ int h_in[RSZ];
    int c = blockIdx.x / RANGES, r = blockIdx.x % RANGES;
    int lo = r * RSZ;
    for (int i = threadIdx.x; i < RSZ; i += 256) { h_out[i] = 0; h_in[i] = 0; }
    __syncthreads();
    const int4* s4 = (const int4*)(src + c * CSZ);
    const int4* d4 = (const int4*)(dst + c * CSZ);
    for (int i = threadIdx.x; i < CSZ / 4; i += 256) {
        int4 s = s4[i], d = d4[i];
        int v;
        v = s.x - lo; if ((unsigned)v < RSZ) atomicAdd(&h_out[v], 1);
        v = s.y - lo; if ((unsigned)v < RSZ) atomicAdd(&h_out[v], 1);
        v = s.z - lo; if ((unsigned)v < RSZ) atomicAdd(&h_out[v], 1);
        v = s.w - lo; if ((unsigned)v < RSZ) atomicAdd(&h_out[v], 1);
        v = d.x - lo; if ((unsigned)v < RSZ) atomicAdd(&h_in[v], 1);
        v = d.y - lo; if ((unsigned)v < RSZ) atomicAdd(&h_in[v], 1);
        v = d.z - lo; if ((unsigned)v < RSZ) atomicAdd(&h_in[v], 1);
        v = d.w - lo; if ((unsigned)v < RSZ) atomicAdd(&h_in[v], 1);
    }
    __syncthreads();
    for (int i = threadIdx.x; i < RSZ; i += 256) {
        g_pout[c * NN + lo + i] = h_out[i];
        g_pin[c * NN + lo + i]  = h_in[i];
    }
}

// ---- Pass B1: reduce partials -> degrees, norms ----
__global__ __launch_bounds__(256) void sums_norms_kernel() {
    int n = blockIdx.x * 256 + threadIdx.x;
    if (n >= NN) return;
    int so = 0, si = 0;
#pragma unroll
    for (int c = 0; c < CHUNKS; ++c) { so += g_pout[c * NN + n]; si += g_pin[c * NN + n]; }
    g_deg_in[n] = si;
    g_out_norm[n] = rsqrtf((float)max(so, 1));
    g_in_norm[n]  = rsqrtf((float)max(si, 1));
}

// ---- 3-phase parallel exclusive scan of g_deg_in -> g_rowptr ----
__global__ __launch_bounds__(256) void scan_phase1() {
    __shared__ int wsum[4];
    int b = blockIdx.x, t = threadIdx.x;
    int base = b * 1024 + t * 4;
    int s = 0;
    if (base + 3 < NN) {
        int4 v = *(const int4*)&g_deg_in[base];
        s = v.x + v.y + v.z + v.w;
    } else {
#pragma unroll
        for (int k = 0; k < 4; ++k)
            if (base + k < NN) s += g_deg_in[base + k];
    }
#pragma unroll
    for (int off = 32; off; off >>= 1) s += __shfl_xor(s, off, 64);
    if ((t & 63) == 0) wsum[t >> 6] = s;
    __syncthreads();
    if (t == 0) g_blocksum[b] = wsum[0] + wsum[1] + wsum[2] + wsum[3];
}

__global__ __launch_bounds__(64) void scan_phase2() {
    int lane = threadIdx.x;
    int own = (lane < SCAN_B) ? g_blocksum[lane] : 0;
    int v = own;
#pragma unroll
    for (int off = 1; off < 64; off <<= 1) {
        int n = __shfl_up(v, off, 64);
        if (lane >= off) v += n;
    }
    if (lane < SCAN_B) g_blockoff[lane] = v - own;
    if (lane == SCAN_B - 1) g_rowptr[NN] = v;   // total == NE
}

__global__ __launch_bounds__(256) void scan_phase3() {
    __shared__ int sums[256];
    int b = blockIdx.x, t = threadIdx.x;
    int base = b * 1024 + t * 4;
    int v[4];
#pragma unroll
    for (int k = 0; k < 4; ++k) v[k] = (base + k < NN) ? g_deg_in[base + k] : 0;
    int tsum = v[0] + v[1] + v[2] + v[3];
    sums[t] = tsum;
    __syncthreads();
    for (int off = 1; off < 256; off <<= 1) {
        int add = (t >= off) ? sums[t - off] : 0;
        __syncthreads();
        sums[t] += add;
        __syncthreads();
    }
    int excl = sums[t] - tsum + g_blockoff[b];
#pragma unroll
    for (int k = 0; k < 4; ++k) {
        int idx = base + k;
        if (idx < NN) g_rowptr[idx] = excl;
        excl += v[k];
    }
}

// ---- Pass B2: per-chunk cursor bases: base[c][n] = rowptr[n] + sum_{c'<c} pin[c'][n] ----
__global__ __launch_bounds__(256) void base_kernel() {
    int n = blockIdx.x * 256 + threadIdx.x;
    if (n >= NN) return;
    int run = g_rowptr[n];
#pragma unroll
    for (int c = 0; c < CHUNKS; ++c) {
        g_base[c * NN + n] = run;
        run += g_pin[c * NN + n];
    }
}

// ---- Pass C: CSR placement via LDS cursors (no device-scope atomics) ----
__global__ __launch_bounds__(256) void place_lds_kernel(const int* __restrict__ src,
                                                        const int* __restrict__ dst) {
    __shared__ int cur[RSZ];
    int c = blockIdx.x / RANGES, r = blockIdx.x % RANGES;
    int lo = r * RSZ;
    for (int i = threadIdx.x; i < RSZ; i += 256) cur[i] = g_base[c * NN + lo + i];
    __syncthreads();
    const int4* s4 = (const int4*)(src + c * CSZ);
    const int4* d4 = (const int4*)(dst + c * CSZ);
    for (int i = threadIdx.x; i < CSZ / 4; i += 256) {
        int4 s = s4[i], d = d4[i];
        int v, p;
        v = d.x - lo; if ((unsigned)v < RSZ) { p = atomicAdd(&cur[v], 1); g_esrc[p] = s.x; }
        v = d.y - lo; if ((unsigned)v < RSZ) { p = atomicAdd(&cur[v], 1); g_esrc[p] = s.y; }
        v = d.z - lo; if ((unsigned)v < RSZ) { p = atomicAdd(&cur[v], 1); g_esrc[p] = s.z; }
        v = d.w - lo; if ((unsigned)v < RSZ) { p = atomicAdd(&cur[v], 1); g_esrc[p] = s.w; }
    }
}

// C[M x N](fp16) = (A * out_norm[:,None]) @ W.
// A: fp32 ext (layer 0) or fp16 hbuf. W: [128 x N] fp32. fp32 accumulate.
template <int N, bool AEXT>
__global__ __launch_bounds__(256) void gemm_scaled(const float* __restrict__ Aext,
                                                   int a_ib, int c_ib,
                                                   const float* __restrict__ Wg,
                                                   int M) {
    constexpr int TM = 4096 / N;   // 32 (N=128) or 64 (N=64)
    constexpr int CG = N / 4;      // 4-col groups per row
    __shared__ float Wl[64 * N];
    __shared__ float Al[TM * 64];

    const int tid = threadIdx.x;
    const int row0 = blockIdx.x * TM;
    const int tr = tid / CG;
    const int tc = tid % CG;
    const int r0 = tr * 4;

    float acc[4][4] = {};
    const float4* W4 = (const float4*)Wg;
    const float4* A4 = AEXT ? (const float4*)Aext : nullptr;
    const uint2* Ah = AEXT ? nullptr : (const uint2*)hbuf(a_ib);
    __half* C = hbuf(c_ib);

    for (int ph = 0; ph < 2; ++ph) {
        for (int i = tid; i < 64 * N / 4; i += 256) {
            ((float4*)Wl)[i] = W4[ph * 16 * N + i];
        }
        for (int i = tid; i < TM * 16; i += 256) {
            int r = i >> 4, c4 = i & 15;
            int gr = row0 + r;
            float4 v = make_float4(0.f, 0.f, 0.f, 0.f);
            if (gr < M) {
                float s = g_out_norm[gr];
                if (AEXT) {
                    v = A4[gr * 32 + ph * 16 + c4];
                } else {
                    uint2 u = Ah[gr * 32 + ph * 16 + c4];
                    float2 f0 = __half22float2(*(const __half2*)&u.x);
                    float2 f1 = __half22float2(*(const __half2*)&u.y);
                    v = make_float4(f0.x, f0.y, f1.x, f1.y);
                }
                v.x *= s; v.y *= s; v.z *= s; v.w *= s;
            }
            ((float4*)Al)[i] = v;
        }
        __syncthreads();

        const float4* Al4 = (const float4*)Al;
        const float4* Wl4 = (const float4*)Wl;
#pragma unroll 2
        for (int kk = 0; kk < 16; ++kk) {
            float4 a[4], w[4];
#pragma unroll
            for (int i = 0; i < 4; ++i) a[i] = Al4[(r0 + i) * 16 + kk];
#pragma unroll
            for (int j = 0; j < 4; ++j) w[j] = Wl4[(4 * kk + j) * CG + tc];
#pragma unroll
            for (int i = 0; i < 4; ++i) {
                acc[i][0] += a[i].x * w[0].x + a[i].y * w[1].x + a[i].z * w[2].x + a[i].w * w[3].x;
                acc[i][1] += a[i].x * w[0].y + a[i].y * w[1].y + a[i].z * w[2].y + a[i].w * w[3].y;
                acc[i][2] += a[i].x * w[0].z + a[i].y * w[1].z + a[i].z * w[2].z + a[i].w * w[3].z;
                acc[i][3] += a[i].x * w[0].w + a[i].y * w[1].w + a[i].z * w[2].w + a[i].w * w[3].w;
            }
        }
        __syncthreads();
    }

#pragma unroll
    for (int i = 0; i < 4; ++i) {
        int gr = row0 + r0 + i;
        if (gr < M) {
            __half2 ha = __floats2half2_rn(acc[i][0], acc[i][1]);
            __half2 hb = __floats2half2_rn(acc[i][2], acc[i][3]);
            uint2 o = make_uint2(*(const unsigned int*)&ha, *(const unsigned int*)&hb);
            ((uint2*)C)[gr * CG + tc] = o;
        }
    }
}

// Fused: gather(CSR, fp16 128-dim) -> *in_norm + b -> relu -> LN -> fp16 write. 1 wave/node.
__global__ __launch_bounds__(256) void gather_ln_kernel(int s_ib, int d_ib,
                                                        const float* __restrict__ b,
                                                        const float* __restrict__ ln_s,
                                                        const float* __restrict__ ln_b) {
    int wave = threadIdx.x >> 6;
    int lane = threadIdx.x & 63;
    int node = blockIdx.x * 4 + wave;
    if (node >= NN) return;
    const unsigned int* Hu = (const unsigned int*)hbuf(s_ib);  // half2 per lane, 64/row
    int beg = g_rowptr[node], end = g_rowptr[node + 1];
    float ax = 0.f, ay = 0.f;
    int j = beg;
    for (; j + 3 < end; j += 4) {
        int s0 = g_esrc[j], s1 = g_esrc[j + 1], s2 = g_esrc[j + 2], s3 = g_esrc[j + 3];
        unsigned int u0 = Hu[s0 * 64 + lane];
        unsigned int u1 = Hu[s1 * 64 + lane];
        unsigned int u2 = Hu[s2 * 64 + lane];
        unsigned int u3 = Hu[s3 * 64 + lane];
        float2 f0 = __half22float2(*(const __half2*)&u0);
        float2 f1 = __half22float2(*(const __half2*)&u1);
        float2 f2 = __half22float2(*(const __half2*)&u2);
        float2 f3 = __half22float2(*(const __half2*)&u3);
        ax += (f0.x + f1.x) + (f2.x + f3.x);
        ay += (f0.y + f1.y) + (f2.y + f3.y);
    }
    for (; j < end; ++j) {
        unsigned int u = Hu[g_esrc[j] * 64 + lane];
        float2 f = __half22float2(*(const __half2*)&u);
        ax += f.x; ay += f.y;
    }
    float nrm = g_in_norm[node];
    int c = lane * 2;
    float vx = fmaxf(ax * nrm + b[c], 0.f);
    float vy = fmaxf(ay * nrm + b[c + 1], 0.f);
    float s = vx + vy;
    float sq = vx * vx + vy * vy;
#pragma unroll
    for (int off = 32; off > 0; off >>= 1) {
        s  += __shfl_xor(s, off, 64);
        sq += __shfl_xor(sq, off, 64);
    }
    float mean = s * (1.f / 128.f);
    float var = sq * (1.f / 128.f) - mean * mean;
    float inv = rsqrtf(var + LN_EPS);
    float ox = (vx - mean) * inv * ln_s[c] + ln_b[c];
    float oy = (vy - mean) * inv * ln_s[c + 1] + ln_b[c + 1];
    __half2 h = __floats2half2_rn(ox, oy);
    ((unsigned int*)hbuf(d_ib))[node * 64 + lane] = *(const unsigned int*)&h;
}

// Fused final: gather(CSR, fp16 64-dim) -> *in_norm + b2 -> relu -> fp32 out. 1 wave/node.
__global__ __launch_bounds__(256) void GCN_63831803953156_kernel(int s_ib,
                                                                 const float* __restrict__ b2,
                                                                 float* __restrict__ out) {
    int wave = threadIdx.x >> 6;
    int lane = threadIdx.x & 63;
    int node = blockIdx.x * 4 + wave;
    if (node >= NN) return;
    const unsigned short* Hs = (const unsigned short*)hbuf(s_ib);  // 1 half per lane, 64/row
    int beg = g_rowptr[node], end = g_rowptr[node + 1];
    float acc = 0.f;
    int j = beg;
    for (; j + 3 < end; j += 4) {
        int s0 = g_esrc[j], s1 = g_esrc[j + 1], s2 = g_esrc[j + 2], s3 = g_esrc[j + 3];
        unsigned short u0 = Hs[s0 * 64 + lane];
        unsigned short u1 = Hs[s1 * 64 + lane];
        unsigned short u2 = Hs[s2 * 64 + lane];
        unsigned short u3 = Hs[s3 * 64 + lane];
        acc += (__half2float(*(const __half*)&u0) + __half2float(*(const __half*)&u1)) +
               (__half2float(*(const __half*)&u2) + __half2float(*(const __half*)&u3));
    }
    for (; j < end; ++j) {
        unsigned short u = Hs[g_esrc[j] * 64 + lane];
        acc += __half2float(*(const __half*)&u);
    }
    float v = fmaxf(acc * g_in_norm[node] + b2[lane], 0.f);
    out[node * 64 + lane] = v;
}

extern "C" void kernel_launch(void* const* d_in, const int* in_sizes, int n_in,
                              void* d_out, int out_size, void* d_ws, size_t ws_size,
                              hipStream_t stream) {
    const float* x   = (const float*)d_in[0];
    const int* src   = (const int*)d_in[1];
    const int* dst   = (const int*)d_in[2];
    const float* W0  = (const float*)d_in[3];
    const float* b0  = (const float*)d_in[4];
    const float* W1  = (const float*)d_in[5];
    const float* b1  = (const float*)d_in[6];
    const float* W2  = (const float*)d_in[7];
    const float* b2  = (const float*)d_in[8];
    const float* ln_s = (const float*)d_in[9];
    const float* ln_b = (const float*)d_in[10];
    (void)d_ws; (void)ws_size; (void)in_sizes; (void)n_in; (void)out_size;

    // CSR build: privatized histograms -> norms -> scan -> bases -> LDS-cursor place
    histo_kernel<<<CHUNKS * RANGES, 256, 0, stream>>>(src, dst);
    sums_norms_kernel<<<(NN + 255) / 256, 256, 0, stream>>>();
    scan_phase1<<<SCAN_B, 256, 0, stream>>>();
    scan_phase2<<<1, 64, 0, stream>>>();
    scan_phase3<<<SCAN_B, 256, 0, stream>>>();
    base_kernel<<<(NN + 255) / 256, 256, 0, stream>>>();
    place_lds_kernel<<<CHUNKS * RANGES, 256, 0, stream>>>(src, dst);

    // layer 0: gemm X->H0, fused gather+LN H0->H1
    gemm_scaled<128, true><<<(NN + 31) / 32, 256, 0, stream>>>(x, -1, 0, W0, NN);
    gather_ln_kernel<<<(NN + 3) / 4, 256, 0, stream>>>(0, 1, b0, ln_s, ln_b);

    // layer 1: gemm H1->H0, fused gather+LN H0->H1
    gemm_scaled<128, false><<<(NN + 31) / 32, 256, 0, stream>>>(nullptr, 1, 0, W1, NN);
    gather_ln_kernel<<<(NN + 3) / 4, 256, 0, stream>>>(0, 1, b1, ln_s, ln_b);

    // layer 2 (128->64): gemm H1->H0, fused gather+relu H0->out
    gemm_scaled<64, false><<<(NN + 63) / 64, 256, 0, stream>>>(nullptr, 1, 0, W2, NN);
    GCN_63831803953156_kernel<<<(NN + 3) / 4, 256, 0, stream>>>(0, b2, (float*)d_out);
}

// Round 8
// 285.986 us; speedup vs baseline: 2.0517x; 1.1948x over previous
//
#include <hip/hip_runtime.h>
#include <hip/hip_fp16.h>

#define NN 50000
#define NE 600000
#define LN_EPS 1e-5f
#define SCAN_B 49    // 49 blocks x 1024 elements covers 50176 >= NN
#define RANGES 8     // node ranges of 6250 (8*6250 = 50000)
#define RSZ 6250
#define CHUNKS 16    // edge chunks of 37500 (16*37500 = 600000)
#define CSZ 37500

typedef __attribute__((ext_vector_type(8))) _Float16 half8;
typedef __attribute__((ext_vector_type(4))) float floatx4;

// Module-level device scratch (graph-capture safe).
__device__ __align__(16) __half g_h0[NN * 128];
__device__ __align__(16) __half g_h1[NN * 128];
__device__ __align__(16) int g_deg_in[NN];
__device__ float g_out_norm[NN];
__device__ float g_in_norm[NN];
__device__ int g_rowptr[NN + 1];
__device__ int g_esrc[NE];
__device__ int g_blocksum[SCAN_B];
__device__ int g_blockoff[SCAN_B];
// CSR-build privatized partials (no device-scope atomics in the hot path)
__device__ int g_pout[CHUNKS * NN];
__device__ int g_pin[CHUNKS * NN];
__device__ int g_base[CHUNKS * NN];

__device__ __forceinline__ __half* hbuf(int i) { return i ? g_h1 : g_h0; }

// ---- Pass A: privatized histograms. Block (c,r): LDS-count chunk c's edges in range r ----
__global__ __launch_bounds__(256) void histo_kernel(const int* __restrict__ src,
                                                    const int* __restrict__ dst) {
    __shared__ int h_out[RSZ];
    __shared__ int h_in[RSZ];
    int c = blockIdx.x / RANGES, r = blockIdx.x % RANGES;
    int lo = r * RSZ;
    for (int i = threadIdx.x; i < RSZ; i += 256) { h_out[i] = 0; h_in[i] = 0; }
    __syncthreads();
    const int4* s4 = (const int4*)(src + c * CSZ);
    const int4* d4 = (const int4*)(dst + c * CSZ);
    for (int i = threadIdx.x; i < CSZ / 4; i += 256) {
        int4 s = s4[i], d = d4[i];
        int v;
        v = s.x - lo; if ((unsigned)v < RSZ) atomicAdd(&h_out[v], 1);
        v = s.y - lo; if ((unsigned)v < RSZ) atomicAdd(&h_out[v], 1);
        v = s.z - lo; if ((unsigned)v < RSZ) atomicAdd(&h_out[v], 1);
        v = s.w - lo; if ((unsigned)v < RSZ) atomicAdd(&h_out[v], 1);
        v = d.x - lo; if ((unsigned)v < RSZ) atomicAdd(&h_in[v], 1);
        v = d.y - lo; if ((unsigned)v < RSZ) atomicAdd(&h_in[v], 1);
        v = d.z - lo; if ((unsigned)v < RSZ) atomicAdd(&h_in[v], 1);
        v = d.w - lo; if ((unsigned)v < RSZ) atomicAdd(&h_in[v], 1);
    }
    __syncthreads();
    for (int i = threadIdx.x; i < RSZ; i += 256) {
        g_pout[c * NN + lo + i] = h_out[i];
        g_pin[c * NN + lo + i]  = h_in[i];
    }
}

// ---- Pass B1: reduce partials -> degrees, norms ----
__global__ __launch_bounds__(256) void sums_norms_kernel() {
    int n = blockIdx.x * 256 + threadIdx.x;
    if (n >= NN) return;
    int so = 0, si = 0;
#pragma unroll
    for (int c = 0; c < CHUNKS; ++c) { so += g_pout[c * NN + n]; si += g_pin[c * NN + n]; }
    g_deg_in[n] = si;
    g_out_norm[n] = rsqrtf((float)max(so, 1));
    g_in_norm[n]  = rsqrtf((float)max(si, 1));
}

// ---- 3-phase parallel exclusive scan of g_deg_in -> g_rowptr ----
__global__ __launch_bounds__(256) void scan_phase1() {
    __shared__ int wsum[4];
    int b = blockIdx.x, t = threadIdx.x;
    int base = b * 1024 + t * 4;
    int s = 0;
    if (base + 3 < NN) {
        int4 v = *(const int4*)&g_deg_in[base];
        s = v.x + v.y + v.z + v.w;
    } else {
#pragma unroll
        for (int k = 0; k < 4; ++k)
            if (base + k < NN) s += g_deg_in[base + k];
    }
#pragma unroll
    for (int off = 32; off; off >>= 1) s += __shfl_xor(s, off, 64);
    if ((t & 63) == 0) wsum[t >> 6] = s;
    __syncthreads();
    if (t == 0) g_blocksum[b] = wsum[0] + wsum[1] + wsum[2] + wsum[3];
}

__global__ __launch_bounds__(64) void scan_phase2() {
    int lane = threadIdx.x;
    int own = (lane < SCAN_B) ? g_blocksum[lane] : 0;
    int v = own;
#pragma unroll
    for (int off = 1; off < 64; off <<= 1) {
        int n = __shfl_up(v, off, 64);
        if (lane >= off) v += n;
    }
    if (lane < SCAN_B) g_blockoff[lane] = v - own;
    if (lane == SCAN_B - 1) g_rowptr[NN] = v;   // total == NE
}

__global__ __launch_bounds__(256) void scan_phase3() {
    __shared__ int sums[256];
    int b = blockIdx.x, t = threadIdx.x;
    int base = b * 1024 + t * 4;
    int v[4];
#pragma unroll
    for (int k = 0; k < 4; ++k) v[k] = (base + k < NN) ? g_deg_in[base + k] : 0;
    int tsum = v[0] + v[1] + v[2] + v[3];
    sums[t] = tsum;
    __syncthreads();
    for (int off = 1; off < 256; off <<= 1) {
        int add = (t >= off) ? sums[t - off] : 0;
        __syncthreads();
        sums[t] += add;
        __syncthreads();
    }
    int excl = sums[t] - tsum + g_blockoff[b];
#pragma unroll
    for (int k = 0; k < 4; ++k) {
        int idx = base + k;
        if (idx < NN) g_rowptr[idx] = excl;
        excl += v[k];
    }
}

// ---- Pass B2: per-chunk cursor bases: base[c][n] = rowptr[n] + sum_{c'<c} pin[c'][n] ----
__global__ __launch_bounds__(256) void base_kernel() {
    int n = blockIdx.x * 256 + threadIdx.x;
    if (n >= NN) return;
    int run = g_rowptr[n];
#pragma unroll
    for (int c = 0; c < CHUNKS; ++c) {
        g_base[c * NN + n] = run;
        run += g_pin[c * NN + n];
    }
}

// ---- Pass C: CSR placement via LDS cursors (no device-scope atomics) ----
__global__ __launch_bounds__(256) void place_lds_kernel(const int* __restrict__ src,
                                                        const int* __restrict__ dst) {
    __shared__ int cur[RSZ];
    int c = blockIdx.x / RANGES, r = blockIdx.x % RANGES;
    int lo = r * RSZ;
    for (int i = threadIdx.x; i < RSZ; i += 256) cur[i] = g_base[c * NN + lo + i];
    __syncthreads();
    const int4* s4 = (const int4*)(src + c * CSZ);
    const int4* d4 = (const int4*)(dst + c * CSZ);
    for (int i = threadIdx.x; i < CSZ / 4; i += 256) {
        int4 s = s4[i], d = d4[i];
        int v, p;
        v = d.x - lo; if ((unsigned)v < RSZ) { p = atomicAdd(&cur[v], 1); g_esrc[p] = s.x; }
        v = d.y - lo; if ((unsigned)v < RSZ) { p = atomicAdd(&cur[v], 1); g_esrc[p] = s.y; }
        v = d.z - lo; if ((unsigned)v < RSZ) { p = atomicAdd(&cur[v], 1); g_esrc[p] = s.z; }
        v = d.w - lo; if ((unsigned)v < RSZ) { p = atomicAdd(&cur[v], 1); g_esrc[p] = s.w; }
    }
}

// ---- MFMA GEMM: C[M x N](fp16) = (A * out_norm[:,None]) @ W ----
// A: fp32 ext (layer 0) or fp16 hbuf. W fp32 -> fp16 in LDS (swizzled for contiguous B-frags).
// out_norm folded into epilogue (C row scale == A row scale by linearity).
// Wave computes 16 rows x N cols via v_mfma_f32_16x16x32_f16; block = 4 waves = 64 rows.
template <int N, bool AEXT>
__global__ __launch_bounds__(256) void gemm_mfma(const float* __restrict__ Aext,
                                                 int a_ib, int c_ib,
                                                 const float* __restrict__ Wg,
                                                 int M) {
    constexpr int NT = N / 16;             // 8 (N=128) or 4 (N=64)
    constexpr int LOGN = (N == 128) ? 7 : 6;
    __shared__ _Float16 Wl[128 * N];       // swizzled: idx = ((k>>3)*N + n)*8 + (k&7)

    const int tid = threadIdx.x;
    // stage W: coalesced fp32 read, swizzled fp16 LDS write
    for (int e = tid; e < 128 * N; e += 256) {
        int k = e >> LOGN, n = e & (N - 1);
        Wl[(((k >> 3) * N + n) << 3) + (k & 7)] = (_Float16)Wg[e];
    }
    __syncthreads();

    const int wv = tid >> 6, lane = tid & 63;
    const int quad = lane >> 4, mrow = lane & 15;
    const int rowbase = blockIdx.x * 64 + wv * 16;
    const int arow0 = rowbase + mrow;
    const int arow = (arow0 < M) ? arow0 : (M - 1);   // clamp; OOB rows never stored

    floatx4 acc[NT] = {};
    const __half* Ah = AEXT ? nullptr : hbuf(a_ib);

#pragma unroll
    for (int kk = 0; kk < 4; ++kk) {
        const int k0 = kk * 32 + quad * 8;
        half8 afrag;
        if (AEXT) {
            const float4* ap = (const float4*)(Aext + (size_t)arow * 128 + k0);
            float4 f0 = ap[0], f1 = ap[1];
            afrag[0] = (_Float16)f0.x; afrag[1] = (_Float16)f0.y;
            afrag[2] = (_Float16)f0.z; afrag[3] = (_Float16)f0.w;
            afrag[4] = (_Float16)f1.x; afrag[5] = (_Float16)f1.y;
            afrag[6] = (_Float16)f1.z; afrag[7] = (_Float16)f1.w;
        } else {
            afrag = *(const half8*)(Ah + (size_t)arow * 128 + k0);
        }
#pragma unroll
        for (int nt = 0; nt < NT; ++nt) {
            half8 bfrag = *(const half8*)&Wl[(((kk * 4 + quad) * N + nt * 16 + mrow) << 3)];
            acc[nt] = __builtin_amdgcn_mfma_f32_16x16x32_f16(afrag, bfrag, acc[nt], 0, 0, 0);
        }
    }

    // epilogue: D[row=quad*4+r][col=mrow] per tile; scale rows by out_norm
    __half* C = hbuf(c_ib);
#pragma unroll
    for (int r = 0; r < 4; ++r) {
        int crow = rowbase + quad * 4 + r;
        if (crow < M) {
            float s = g_out_norm[crow];
#pragma unroll
            for (int nt = 0; nt < NT; ++nt) {
                float v = acc[nt][r] * s;
                C[(size_t)crow * N + nt * 16 + mrow] = __float2half_rn(v);
            }
        }
    }
}

// Fused: gather(CSR, fp16 128-dim) -> *in_norm + b -> relu -> LN -> fp16 write. 1 wave/node.
__global__ __launch_bounds__(256) void gather_ln_kernel(int s_ib, int d_ib,
                                                        const float* __restrict__ b,
                                                        const float* __restrict__ ln_s,
                                                        const float* __restrict__ ln_b) {
    int wave = threadIdx.x >> 6;
    int lane = threadIdx.x & 63;
    int node = blockIdx.x * 4 + wave;
    if (node >= NN) return;
    const unsigned int* Hu = (const unsigned int*)hbuf(s_ib);  // half2 per lane, 64/row
    int beg = g_rowptr[node], end = g_rowptr[node + 1];
    float ax = 0.f, ay = 0.f;
    int j = beg;
    for (; j + 3 < end; j += 4) {
        int s0 = g_esrc[j], s1 = g_esrc[j + 1], s2 = g_esrc[j + 2], s3 = g_esrc[j + 3];
        unsigned int u0 = Hu[s0 * 64 + lane];
        unsigned int u1 = Hu[s1 * 64 + lane];
        unsigned int u2 = Hu[s2 * 64 + lane];
        unsigned int u3 = Hu[s3 * 64 + lane];
        float2 f0 = __half22float2(*(const __half2*)&u0);
        float2 f1 = __half22float2(*(const __half2*)&u1);
        float2 f2 = __half22float2(*(const __half2*)&u2);
        float2 f3 = __half22float2(*(const __half2*)&u3);
        ax += (f0.x + f1.x) + (f2.x + f3.x);
        ay += (f0.y + f1.y) + (f2.y + f3.y);
    }
    for (; j < end; ++j) {
        unsigned int u = Hu[g_esrc[j] * 64 + lane];
        float2 f = __half22float2(*(const __half2*)&u);
        ax += f.x; ay += f.y;
    }
    float nrm = g_in_norm[node];
    int c = lane * 2;
    float vx = fmaxf(ax * nrm + b[c], 0.f);
    float vy = fmaxf(ay * nrm + b[c + 1], 0.f);
    float s = vx + vy;
    float sq = vx * vx + vy * vy;
#pragma unroll
    for (int off = 32; off > 0; off >>= 1) {
        s  += __shfl_xor(s, off, 64);
        sq += __shfl_xor(sq, off, 64);
    }
    float mean = s * (1.f / 128.f);
    float var = sq * (1.f / 128.f) - mean * mean;
    float inv = rsqrtf(var + LN_EPS);
    float ox = (vx - mean) * inv * ln_s[c] + ln_b[c];
    float oy = (vy - mean) * inv * ln_s[c + 1] + ln_b[c + 1];
    __half2 h = __floats2half2_rn(ox, oy);
    ((unsigned int*)hbuf(d_ib))[node * 64 + lane] = *(const unsigned int*)&h;
}

// Fused final: gather(CSR, fp16 64-dim) -> *in_norm + b2 -> relu -> fp32 out. 1 wave/node.
__global__ __launch_bounds__(256) void GCN_63831803953156_kernel(int s_ib,
                                                                 const float* __restrict__ b2,
                                                                 float* __restrict__ out) {
    int wave = threadIdx.x >> 6;
    int lane = threadIdx.x & 63;
    int node = blockIdx.x * 4 + wave;
    if (node >= NN) return;
    const unsigned short* Hs = (const unsigned short*)hbuf(s_ib);  // 1 half per lane, 64/row
    int beg = g_rowptr[node], end = g_rowptr[node + 1];
    float acc = 0.f;
    int j = beg;
    for (; j + 3 < end; j += 4) {
        int s0 = g_esrc[j], s1 = g_esrc[j + 1], s2 = g_esrc[j + 2], s3 = g_esrc[j + 3];
        unsigned short u0 = Hs[s0 * 64 + lane];
        unsigned short u1 = Hs[s1 * 64 + lane];
        unsigned short u2 = Hs[s2 * 64 + lane];
        unsigned short u3 = Hs[s3 * 64 + lane];
        acc += (__half2float(*(const __half*)&u0) + __half2float(*(const __half*)&u1)) +
               (__half2float(*(const __half*)&u2) + __half2float(*(const __half*)&u3));
    }
    for (; j < end; ++j) {
        unsigned short u = Hs[g_esrc[j] * 64 + lane];
        acc += __half2float(*(const __half*)&u);
    }
    float v = fmaxf(acc * g_in_norm[node] + b2[lane], 0.f);
    out[node * 64 + lane] = v;
}

extern "C" void kernel_launch(void* const* d_in, const int* in_sizes, int n_in,
                              void* d_out, int out_size, void* d_ws, size_t ws_size,
                              hipStream_t stream) {
    const float* x   = (const float*)d_in[0];
    const int* src   = (const int*)d_in[1];
    const int* dst   = (const int*)d_in[2];
    const float* W0  = (const float*)d_in[3];
    const float* b0  = (const float*)d_in[4];
    const float* W1  = (const float*)d_in[5];
    const float* b1  = (const float*)d_in[6];
    const float* W2  = (const float*)d_in[7];
    const float* b2  = (const float*)d_in[8];
    const float* ln_s = (const float*)d_in[9];
    const float* ln_b = (const float*)d_in[10];
    (void)d_ws; (void)ws_size; (void)in_sizes; (void)n_in; (void)out_size;

    // CSR build: privatized histograms -> norms -> scan -> bases -> LDS-cursor place
    histo_kernel<<<CHUNKS * RANGES, 256, 0, stream>>>(src, dst);
    sums_norms_kernel<<<(NN + 255) / 256, 256, 0, stream>>>();
    scan_phase1<<<SCAN_B, 256, 0, stream>>>();
    scan_phase2<<<1, 64, 0, stream>>>();
    scan_phase3<<<SCAN_B, 256, 0, stream>>>();
    base_kernel<<<(NN + 255) / 256, 256, 0, stream>>>();
    place_lds_kernel<<<CHUNKS * RANGES, 256, 0, stream>>>(src, dst);

    const int GB = (NN + 63) / 64;  // 782

    // layer 0: gemm X->H0, fused gather+LN H0->H1
    gemm_mfma<128, true><<<GB, 256, 0, stream>>>(x, -1, 0, W0, NN);
    gather_ln_kernel<<<(NN + 3) / 4, 256, 0, stream>>>(0, 1, b0, ln_s, ln_b);

    // layer 1: gemm H1->H0, fused gather+LN H0->H1
    gemm_mfma<128, false><<<GB, 256, 0, stream>>>(nullptr, 1, 0, W1, NN);
    gather_ln_kernel<<<(NN + 3) / 4, 256, 0, stream>>>(0, 1, b1, ln_s, ln_b);

    // layer 2 (128->64): gemm H1->H0, fused gather+relu H0->out
    gemm_mfma<64, false><<<GB, 256, 0, stream>>>(nullptr, 1, 0, W2, NN);
    GCN_63831803953156_kernel<<<(NN + 3) / 4, 256, 0, stream>>>(0, b2, (float*)d_out);
}

// Round 9
// 267.201 us; speedup vs baseline: 2.1959x; 1.0703x over previous
//
#include <hip/hip_runtime.h>
#include <hip/hip_fp16.h>

#define NN 50000
#define NE 600000
#define LN_EPS 1e-5f
#define SCAN_B 49    // 49 blocks x 1024 nodes covers 50176 >= NN
#define RANGES 8     // node ranges of 6250 (8*6250 = 50000)
#define RSZ 6250
#define CHUNKS 16    // edge chunks of 37500 (16*37500 = 600000)
#define CSZ 37500

typedef __attribute__((ext_vector_type(8))) _Float16 half8;
typedef __attribute__((ext_vector_type(4))) float floatx4;

// Module-level device scratch (graph-capture safe).
__device__ __align__(16) __half g_h0[NN * 128];
__device__ __align__(16) __half g_h1[NN * 128];
__device__ __align__(16) int g_deg_in[NN];
__device__ float g_out_norm[NN];
__device__ float g_in_norm[NN];
__device__ int g_rowptr[NN + 1];
__device__ int g_esrc[NE];
__device__ int g_blocksum[SCAN_B];
__device__ int g_blockoff[SCAN_B];
// CSR-build privatized partials (no device-scope atomics in the hot path)
__device__ int g_pout[CHUNKS * NN];
__device__ int g_pin[CHUNKS * NN];
__device__ int g_base[CHUNKS * NN];

__device__ __forceinline__ __half* hbuf(int i) { return i ? g_h1 : g_h0; }

// ---- Pass A: privatized histograms. Block (c,r): LDS-count chunk c's edges in range r ----
__global__ __launch_bounds__(256) void histo_kernel(const int* __restrict__ src,
                                                    const int* __restrict__ dst) {
    __shared__ int h_out[RSZ];
    __shared__ int h_in[RSZ];
    int c = blockIdx.x / RANGES, r = blockIdx.x % RANGES;
    int lo = r * RSZ;
    for (int i = threadIdx.x; i < RSZ; i += 256) { h_out[i] = 0; h_in[i] = 0; }
    __syncthreads();
    const int4* s4 = (const int4*)(src + c * CSZ);
    const int4* d4 = (const int4*)(dst + c * CSZ);
    for (int i = threadIdx.x; i < CSZ / 4; i += 256) {
        int4 s = s4[i], d = d4[i];
        int v;
        v = s.x - lo; if ((unsigned)v < RSZ) atomicAdd(&h_out[v], 1);
        v = s.y - lo; if ((unsigned)v < RSZ) atomicAdd(&h_out[v], 1);
        v = s.z - lo; if ((unsigned)v < RSZ) atomicAdd(&h_out[v], 1);
        v = s.w - lo; if ((unsigned)v < RSZ) atomicAdd(&h_out[v], 1);
        v = d.x - lo; if ((unsigned)v < RSZ) atomicAdd(&h_in[v], 1);
        v = d.y - lo; if ((unsigned)v < RSZ) atomicAdd(&h_in[v], 1);
        v = d.z - lo; if ((unsigned)v < RSZ) atomicAdd(&h_in[v], 1);
        v = d.w - lo; if ((unsigned)v < RSZ) atomicAdd(&h_in[v], 1);
    }
    __syncthreads();
    for (int i = threadIdx.x; i < RSZ; i += 256) {
        g_pout[c * NN + lo + i] = h_out[i];
        g_pin[c * NN + lo + i]  = h_in[i];
    }
}

// ---- Fused: partial-reduce -> degrees/norms + per-1024 block sums (scan phase 1) ----
__global__ __launch_bounds__(1024) void deg_scan1_kernel() {
    __shared__ int wsum[16];
    int b = blockIdx.x, t = threadIdx.x;
    int n = b * 1024 + t;
    int si = 0;
    if (n < NN) {
        int so = 0;
#pragma unroll
        for (int c = 0; c < CHUNKS; ++c) { so += g_pout[c * NN + n]; si += g_pin[c * NN + n]; }
        g_deg_in[n] = si;
        g_out_norm[n] = rsqrtf((float)max(so, 1));
        g_in_norm[n]  = rsqrtf((float)max(si, 1));
    }
    int s = si;
#pragma unroll
    for (int off = 32; off; off >>= 1) s += __shfl_xor(s, off, 64);
    if ((t & 63) == 0) wsum[t >> 6] = s;
    __syncthreads();
    if (t < 16) {
        int v = wsum[t];
#pragma unroll
        for (int off = 8; off; off >>= 1) v += __shfl_xor(v, off, 16);
        if (t == 0) g_blocksum[b] = v;
    }
}

__global__ __launch_bounds__(64) void scan_phase2() {
    int lane = threadIdx.x;
    int own = (lane < SCAN_B) ? g_blocksum[lane] : 0;
    int v = own;
#pragma unroll
    for (int off = 1; off < 64; off <<= 1) {
        int n = __shfl_up(v, off, 64);
        if (lane >= off) v += n;
    }
    if (lane < SCAN_B) g_blockoff[lane] = v - own;
    if (lane == SCAN_B - 1) g_rowptr[NN] = v;   // total == NE
}

// ---- Fused: local scan -> rowptr + per-chunk cursor bases ----
__global__ __launch_bounds__(256) void scan3_base_kernel() {
    __shared__ int sums[256];
    int b = blockIdx.x, t = threadIdx.x;
    int base = b * 1024 + t * 4;
    int v[4];
#pragma unroll
    for (int k = 0; k < 4; ++k) v[k] = (base + k < NN) ? g_deg_in[base + k] : 0;
    int tsum = v[0] + v[1] + v[2] + v[3];
    sums[t] = tsum;
    __syncthreads();
    for (int off = 1; off < 256; off <<= 1) {
        int add = (t >= off) ? sums[t - off] : 0;
        __syncthreads();
        sums[t] += add;
        __syncthreads();
    }
    int excl = sums[t] - tsum + g_blockoff[b];
#pragma unroll
    for (int k = 0; k < 4; ++k) {
        int idx = base + k;
        if (idx < NN) {
            g_rowptr[idx] = excl;
            int run = excl;
#pragma unroll
            for (int c = 0; c < CHUNKS; ++c) {
                g_base[c * NN + idx] = run;
                run += g_pin[c * NN + idx];
            }
        }
        excl += v[k];
    }
}

// ---- Pass C: CSR placement via LDS cursors (no device-scope atomics) ----
__global__ __launch_bounds__(256) void place_lds_kernel(const int* __restrict__ src,
                                                        const int* __restrict__ dst) {
    __shared__ int cur[RSZ];
    int c = blockIdx.x / RANGES, r = blockIdx.x % RANGES;
    int lo = r * RSZ;
    for (int i = threadIdx.x; i < RSZ; i += 256) cur[i] = g_base[c * NN + lo + i];
    __syncthreads();
    const int4* s4 = (const int4*)(src + c * CSZ);
    const int4* d4 = (const int4*)(dst + c * CSZ);
    for (int i = threadIdx.x; i < CSZ / 4; i += 256) {
        int4 s = s4[i], d = d4[i];
        int v, p;
        v = d.x - lo; if ((unsigned)v < RSZ) { p = atomicAdd(&cur[v], 1); g_esrc[p] = s.x; }
        v = d.y - lo; if ((unsigned)v < RSZ) { p = atomicAdd(&cur[v], 1); g_esrc[p] = s.y; }
        v = d.z - lo; if ((unsigned)v < RSZ) { p = atomicAdd(&cur[v], 1); g_esrc[p] = s.z; }
        v = d.w - lo; if ((unsigned)v < RSZ) { p = atomicAdd(&cur[v], 1); g_esrc[p] = s.w; }
    }
}

// ---- MFMA GEMM: C[M x N](fp16) = (A * out_norm[:,None]) @ W ----
template <int N, bool AEXT>
__global__ __launch_bounds__(256) void gemm_mfma(const float* __restrict__ Aext,
                                                 int a_ib, int c_ib,
                                                 const float* __restrict__ Wg,
                                                 int M) {
    constexpr int NT = N / 16;             // 8 (N=128) or 4 (N=64)
    constexpr int LOGN = (N == 128) ? 7 : 6;
    __shared__ _Float16 Wl[128 * N];       // swizzled: idx = ((k>>3)*N + n)*8 + (k&7)

    const int tid = threadIdx.x;
    for (int e = tid; e < 128 * N; e += 256) {
        int k = e >> LOGN, n = e & (N - 1);
        Wl[(((k >> 3) * N + n) << 3) + (k & 7)] = (_Float16)Wg[e];
    }
    __syncthreads();

    const int wv = tid >> 6, lane = tid & 63;
    const int quad = lane >> 4, mrow = lane & 15;
    const int rowbase = blockIdx.x * 64 + wv * 16;
    const int arow0 = rowbase + mrow;
    const int arow = (arow0 < M) ? arow0 : (M - 1);   // clamp; OOB rows never stored

    floatx4 acc[NT] = {};
    const __half* Ah = AEXT ? nullptr : hbuf(a_ib);

#pragma unroll
    for (int kk = 0; kk < 4; ++kk) {
        const int k0 = kk * 32 + quad * 8;
        half8 afrag;
        if (AEXT) {
            const float4* ap = (const float4*)(Aext + (size_t)arow * 128 + k0);
            float4 f0 = ap[0], f1 = ap[1];
            afrag[0] = (_Float16)f0.x; afrag[1] = (_Float16)f0.y;
            afrag[2] = (_Float16)f0.z; afrag[3] = (_Float16)f0.w;
            afrag[4] = (_Float16)f1.x; afrag[5] = (_Float16)f1.y;
            afrag[6] = (_Float16)f1.z; afrag[7] = (_Float16)f1.w;
        } else {
            afrag = *(const half8*)(Ah + (size_t)arow * 128 + k0);
        }
#pragma unroll
        for (int nt = 0; nt < NT; ++nt) {
            half8 bfrag = *(const half8*)&Wl[(((kk * 4 + quad) * N + nt * 16 + mrow) << 3)];
            acc[nt] = __builtin_amdgcn_mfma_f32_16x16x32_f16(afrag, bfrag, acc[nt], 0, 0, 0);
        }
    }

    __half* C = hbuf(c_ib);
#pragma unroll
    for (int r = 0; r < 4; ++r) {
        int crow = rowbase + quad * 4 + r;
        if (crow < M) {
            float s = g_out_norm[crow];
#pragma unroll
            for (int nt = 0; nt < NT; ++nt) {
                float v = acc[nt][r] * s;
                C[(size_t)crow * N + nt * 16 + mrow] = __float2half_rn(v);
            }
        }
    }
}

// Fused: gather(CSR, fp16 128-dim) -> *in_norm + b -> relu -> LN -> fp16 write.
// 2 nodes/wave, 32 lanes/node, uint2 (4 halves) per lane. 8 nodes/block.
__global__ __launch_bounds__(256) void gather_ln_kernel(int s_ib, int d_ib,
                                                        const float* __restrict__ b,
                                                        const float* __restrict__ ln_s,
                                                        const float* __restrict__ ln_b) {
    int wave = threadIdx.x >> 6;
    int lane = threadIdx.x & 63;
    int sub = lane >> 5, sl = lane & 31;
    int node = blockIdx.x * 8 + wave * 2 + sub;   // NN = 50000 = 6250 * 8, always valid
    const uint2* Hu = (const uint2*)hbuf(s_ib);   // 32 uint2 per 128-dim row
    int beg = g_rowptr[node], end = g_rowptr[node + 1];
    float a0 = 0.f, a1 = 0.f, a2 = 0.f, a3 = 0.f;
    int j = beg;
    for (; j + 3 < end; j += 4) {
        int s0 = g_esrc[j], s1 = g_esrc[j + 1], s2 = g_esrc[j + 2], s3 = g_esrc[j + 3];
        uint2 u0 = Hu[s0 * 32 + sl];
        uint2 u1 = Hu[s1 * 32 + sl];
        uint2 u2 = Hu[s2 * 32 + sl];
        uint2 u3 = Hu[s3 * 32 + sl];
        float2 p0 = __half22float2(*(const __half2*)&u0.x), q0 = __half22float2(*(const __half2*)&u0.y);
        float2 p1 = __half22float2(*(const __half2*)&u1.x), q1 = __half22float2(*(const __half2*)&u1.y);
        float2 p2 = __half22float2(*(const __half2*)&u2.x), q2 = __half22float2(*(const __half2*)&u2.y);
        float2 p3 = __half22float2(*(const __half2*)&u3.x), q3 = __half22float2(*(const __half2*)&u3.y);
        a0 += (p0.x + p1.x) + (p2.x + p3.x);
        a1 += (p0.y + p1.y) + (p2.y + p3.y);
        a2 += (q0.x + q1.x) + (q2.x + q3.x);
        a3 += (q0.y + q1.y) + (q2.y + q3.y);
    }
    for (; j < end; ++j) {
        uint2 u = Hu[g_esrc[j] * 32 + sl];
        float2 p = __half22float2(*(const __half2*)&u.x), q = __half22float2(*(const __half2*)&u.y);
        a0 += p.x; a1 += p.y; a2 += q.x; a3 += q.y;
    }
    float nrm = g_in_norm[node];
    float4 bb = ((const float4*)b)[sl];
    float v0 = fmaxf(a0 * nrm + bb.x, 0.f);
    float v1 = fmaxf(a1 * nrm + bb.y, 0.f);
    float v2 = fmaxf(a2 * nrm + bb.z, 0.f);
    float v3 = fmaxf(a3 * nrm + bb.w, 0.f);
    float s = (v0 + v1) + (v2 + v3);
    float sq = (v0 * v0 + v1 * v1) + (v2 * v2 + v3 * v3);
#pragma unroll
    for (int off = 16; off > 0; off >>= 1) {     // reduce within 32-lane half
        s  += __shfl_xor(s, off, 64);
        sq += __shfl_xor(sq, off, 64);
    }
    float mean = s * (1.f / 128.f);
    float var = sq * (1.f / 128.f) - mean * mean;
    float inv = rsqrtf(var + LN_EPS);
    float4 ls = ((const float4*)ln_s)[sl];
    float4 lb = ((const float4*)ln_b)[sl];
    float o0 = (v0 - mean) * inv * ls.x + lb.x;
    float o1 = (v1 - mean) * inv * ls.y + lb.y;
    float o2 = (v2 - mean) * inv * ls.z + lb.z;
    float o3 = (v3 - mean) * inv * ls.w + lb.w;
    __half2 h0 = __floats2half2_rn(o0, o1);
    __half2 h1 = __floats2half2_rn(o2, o3);
    uint2 o = make_uint2(*(const unsigned int*)&h0, *(const unsigned int*)&h1);
    ((uint2*)hbuf(d_ib))[node * 32 + sl] = o;
}

// Fused final: gather(CSR, fp16 64-dim) -> *in_norm + b2 -> relu -> fp32 float4 out.
// 4 nodes/wave, 16 lanes/node, uint2 loads. 16 nodes/block.
__global__ __launch_bounds__(256) void GCN_63831803953156_kernel(int s_ib,
                                                                 const float* __restrict__ b2,
                                                                 float* __restrict__ out) {
    int wave = threadIdx.x >> 6;
    int lane = threadIdx.x & 63;
    int sub = lane >> 4, sl = lane & 15;
    int node = blockIdx.x * 16 + wave * 4 + sub;  // NN = 50000 = 3125 * 16, always valid
    const uint2* Hu = (const uint2*)hbuf(s_ib);   // 16 uint2 per 64-dim row
    int beg = g_rowptr[node], end = g_rowptr[node + 1];
    float a0 = 0.f, a1 = 0.f, a2 = 0.f, a3 = 0.f;
    int j = beg;
    for (; j + 3 < end; j += 4) {
        int s0 = g_esrc[j], s1 = g_esrc[j + 1], s2 = g_esrc[j + 2], s3 = g_esrc[j + 3];
        uint2 u0 = Hu[s0 * 16 + sl];
        uint2 u1 = Hu[s1 * 16 + sl];
        uint2 u2 = Hu[s2 * 16 + sl];
        uint2 u3 = Hu[s3 * 16 + sl];
        float2 p0 = __half22float2(*(const __half2*)&u0.x), q0 = __half22float2(*(const __half2*)&u0.y);
        float2 p1 = __half22float2(*(const __half2*)&u1.x), q1 = __half22float2(*(const __half2*)&u1.y);
        float2 p2 = __half22float2(*(const __half2*)&u2.x), q2 = __half22float2(*(const __half2*)&u2.y);
        float2 p3 = __half22float2(*(const __half2*)&u3.x), q3 = __half22float2(*(const __half2*)&u3.y);
        a0 += (p0.x + p1.x) + (p2.x + p3.x);
        a1 += (p0.y + p1.y) + (p2.y + p3.y);
        a2 += (q0.x + q1.x) + (q2.x + q3.x);
        a3 += (q0.y + q1.y) + (q2.y + q3.y);
    }
    for (; j < end; ++j) {
        uint2 u = Hu[g_esrc[j] * 16 + sl];
        float2 p = __half22float2(*(const __half2*)&u.x), q = __half22float2(*(const __half2*)&u.y);
        a0 += p.x; a1 += p.y; a2 += q.x; a3 += q.y;
    }
    float nrm = g_in_norm[node];
    float4 bb = ((const float4*)b2)[sl];
    float4 o;
    o.x = fmaxf(a0 * nrm + bb.x, 0.f);
    o.y = fmaxf(a1 * nrm + bb.y, 0.f);
    o.z = fmaxf(a2 * nrm + bb.z, 0.f);
    o.w = fmaxf(a3 * nrm + bb.w, 0.f);
    ((float4*)out)[node * 16 + sl] = o;
}

extern "C" void kernel_launch(void* const* d_in, const int* in_sizes, int n_in,
                              void* d_out, int out_size, void* d_ws, size_t ws_size,
                              hipStream_t stream) {
    const float* x   = (const float*)d_in[0];
    const int* src   = (const int*)d_in[1];
    const int* dst   = (const int*)d_in[2];
    const float* W0  = (const float*)d_in[3];
    const float* b0  = (const float*)d_in[4];
    const float* W1  = (const float*)d_in[5];
    const float* b1  = (const float*)d_in[6];
    const float* W2  = (const float*)d_in[7];
    const float* b2  = (const float*)d_in[8];
    const float* ln_s = (const float*)d_in[9];
    const float* ln_b = (const float*)d_in[10];
    (void)d_ws; (void)ws_size; (void)in_sizes; (void)n_in; (void)out_size;

    // CSR build: histograms -> fused deg/norm/scan1 -> scan2 -> fused scan3+base -> place
    histo_kernel<<<CHUNKS * RANGES, 256, 0, stream>>>(src, dst);
    deg_scan1_kernel<<<SCAN_B, 1024, 0, stream>>>();
    scan_phase2<<<1, 64, 0, stream>>>();
    scan3_base_kernel<<<SCAN_B, 256, 0, stream>>>();
    place_lds_kernel<<<CHUNKS * RANGES, 256, 0, stream>>>(src, dst);

    const int GB = (NN + 63) / 64;  // 782

    // layer 0: gemm X->H0, fused gather+LN H0->H1
    gemm_mfma<128, true><<<GB, 256, 0, stream>>>(x, -1, 0, W0, NN);
    gather_ln_kernel<<<NN / 8, 256, 0, stream>>>(0, 1, b0, ln_s, ln_b);

    // layer 1: gemm H1->H0, fused gather+LN H0->H1
    gemm_mfma<128, false><<<GB, 256, 0, stream>>>(nullptr, 1, 0, W1, NN);
    gather_ln_kernel<<<NN / 8, 256, 0, stream>>>(0, 1, b1, ln_s, ln_b);

    // layer 2 (128->64): gemm H1->H0, fused gather+relu H0->out
    gemm_mfma<64, false><<<GB, 256, 0, stream>>>(nullptr, 1, 0, W2, NN);
    GCN_63831803953156_kernel<<<NN / 16, 256, 0, stream>>>(0, b2, (float*)d_out);
}